// Round 7
// baseline (115.984 us; speedup 1.0000x reference)
//
#include <hip/hip_runtime.h>
#include <math.h>

#define D_DIM 128
#define A_DIM 128
#define SPLIT 4           // blocks per segment
#define NTHREADS 256      // 4 waves per block
#define WPS (SPLIT * 4)   // independent workers (waves) per segment = 16
#define PSTRIDE 132       // floats per partial record: o[128], m, denom, pad

typedef _Float16 f16x8 __attribute__((ext_vector_type(8)));
typedef __attribute__((ext_vector_type(4))) float f32x4;

__device__ __forceinline__ float fast_tanh(float v) {
    float e = __expf(2.0f * v);
    return 1.0f - 2.0f * __builtin_amdgcn_rcpf(e + 1.0f);
}

__device__ __forceinline__ int lower_bound_i32(const int* __restrict__ arr, int n, int val) {
    int lo = 0, hi = n;
    while (lo < hi) {
        int mid = (lo + hi) >> 1;
        if (arr[mid] < val) lo = mid + 1; else hi = mid;
    }
    return lo;
}

// K0: parallel segment bounds (bidx is sorted)
extern "C" __global__ void __launch_bounds__(256)
seg_bounds_kernel(const int* __restrict__ bidx, int N, int B,
                  int* __restrict__ seg_start)
{
    const int i = blockIdx.x * 256 + threadIdx.x;
    if (i <= B) seg_start[i] = lower_bound_i32(bidx, N, i);
}

// K1: per-(segment, quarter) partial. Each WAVE is an independent worker
// over 16-row tiles with its own online softmax state -> NO barriers in the
// main loop (R5's per-tile __syncthreads drained vmcnt and killed overlap).
// scores via fp16 2-term-split MFMA (x = ah+al, W1 fp16); b2 cancels.
extern "C" __global__ void __launch_bounds__(NTHREADS)
fused_partial_kernel(const float* __restrict__ x,
                     const int* __restrict__ seg_start,
                     const float* __restrict__ W1,
                     const float* __restrict__ b1,
                     const float* __restrict__ W2,
                     float* __restrict__ part,
                     int N)
{
    __shared__ _Float16 w1s[A_DIM * D_DIM];   // 32 KB, [col][k] XOR-swizzled
    __shared__ float sB1[A_DIM];
    __shared__ float sW2[A_DIM];
    __shared__ float o_red[16 * 32];          // 2 KB epilogue reduce
    __shared__ float s_m[4], s_d[4];

    const int tid = threadIdx.x;
    const int b   = blockIdx.x >> 2;          // segment
    const int q   = blockIdx.x & (SPLIT - 1); // quarter

    if (tid < A_DIM) { sB1[tid] = b1[tid]; sW2[tid] = W2[tid]; }

    // stage W1: read coalesced [k][c], write transposed+swizzled fp16
    for (int item = tid; item < A_DIM * 16; item += NTHREADS) {
        const int c = item & (A_DIM - 1);
        const int chunk = item >> 7;          // 16B chunk along k (0..15)
        f16x8 vh;
        #pragma unroll
        for (int j = 0; j < 8; ++j)
            vh[j] = (_Float16)W1[(chunk * 8 + j) * A_DIM + c];
        const int addr = c * 256 + ((chunk ^ (c & 15)) << 4);
        *reinterpret_cast<f16x8*>(reinterpret_cast<char*>(w1s) + addr) = vh;
    }
    __syncthreads();

    const int lo  = seg_start[b];
    const int len = seg_start[b + 1] - lo;
    const int nt  = (len + 15) >> 4;          // 16-row tiles in segment

    const int lane = tid & 63;
    const int wv   = tid >> 6;
    const int lc   = lane & 15;               // A/C row within 16x16 tile
    const int lg   = lane >> 4;               // 0..3 ; k-group
    const int wk   = q * 4 + wv;              // worker id within segment

    float m = -INFINITY;
    float denom = 0.0f;
    float o_part[32];                         // dims ks*32 + lg*8 + j
    #pragma unroll
    for (int v = 0; v < 32; ++v) o_part[v] = 0.0f;

    float4 buf[8];
    if (wk < nt) {   // prologue: this wave's first tile (row = lo+tile*16+lc)
        const int gi = min(lo + wk * 16 + lc, N - 1);
        const float4* xr = reinterpret_cast<const float4*>(x + (size_t)gi * D_DIM);
        #pragma unroll
        for (int ks = 0; ks < 4; ++ks) {
            buf[2*ks]   = xr[ks*8 + lg*2];
            buf[2*ks+1] = xr[ks*8 + lg*2 + 1];
        }
    }

    for (int tile = wk; tile < nt; tile += WPS) {
        // split buf -> fp16 hi/lo fragments (k = ks*32 + lg*8 + j)
        f16x8 ah[4], al[4];
        #pragma unroll
        for (int ks = 0; ks < 4; ++ks) {
            float vv[8] = {buf[2*ks].x, buf[2*ks].y, buf[2*ks].z, buf[2*ks].w,
                           buf[2*ks+1].x, buf[2*ks+1].y, buf[2*ks+1].z, buf[2*ks+1].w};
            #pragma unroll
            for (int j = 0; j < 8; ++j) {
                float xv = vv[j];
                _Float16 h = (_Float16)xv;
                ah[ks][j] = h;
                al[ks][j] = (_Float16)(xv - (float)h);
            }
        }

        // prefetch this wave's next tile; no barrier will force-drain it
        const int next = tile + WPS;
        if (next < nt) {
            const int gi = min(lo + next * 16 + lc, N - 1);
            const float4* xr = reinterpret_cast<const float4*>(x + (size_t)gi * D_DIM);
            #pragma unroll
            for (int ks = 0; ks < 4; ++ks) {
                buf[2*ks]   = xr[ks*8 + lg*2];
                buf[2*ks+1] = xr[ks*8 + lg*2 + 1];
            }
        }

        // ---- scores via MFMA: 16 rows x 128 cols ----
        float part0 = 0.f, part1 = 0.f, part2 = 0.f, part3 = 0.f;
        #pragma unroll
        for (int t = 0; t < 8; ++t) {
            f32x4 acc = {0.f, 0.f, 0.f, 0.f};
            const int c = t * 16 + lc;
            const char* base = reinterpret_cast<const char*>(w1s) + c * 256;
            #pragma unroll
            for (int ks = 0; ks < 4; ++ks) {
                const int chunk = ks * 4 + lg;
                f16x8 bh = *reinterpret_cast<const f16x8*>(
                    base + ((chunk ^ (c & 15)) << 4));
                acc = __builtin_amdgcn_mfma_f32_16x16x32_f16(ah[ks], bh, acc, 0, 0, 0);
                acc = __builtin_amdgcn_mfma_f32_16x16x32_f16(al[ks], bh, acc, 0, 0, 0);
            }
            const float b1v = sB1[c], w2v = sW2[c];
            part0 += fast_tanh(acc[0] + b1v) * w2v;
            part1 += fast_tanh(acc[1] + b1v) * w2v;
            part2 += fast_tanh(acc[2] + b1v) * w2v;
            part3 += fast_tanh(acc[3] + b1v) * w2v;
        }
        // reduce over the 16 lc lanes -> part_r = score of row lg*4+r
        #pragma unroll
        for (int mk = 8; mk >= 1; mk >>= 1) {
            part0 += __shfl_xor(part0, mk);
            part1 += __shfl_xor(part1, mk);
            part2 += __shfl_xor(part2, mk);
            part3 += __shfl_xor(part3, mk);
        }
        // mask rows beyond segment end
        const int rbase = tile * 16 + lg * 4;
        const float sc0 = (rbase + 0 < len) ? part0 : -INFINITY;
        const float sc1 = (rbase + 1 < len) ? part1 : -INFINITY;
        const float sc2 = (rbase + 2 < len) ? part2 : -INFINITY;
        const float sc3 = (rbase + 3 < len) ? part3 : -INFINITY;

        // ---- per-wave online softmax (intra-wave shfl only) ----
        float pm = fmaxf(fmaxf(sc0, sc1), fmaxf(sc2, sc3));
        pm = fmaxf(pm, __shfl_xor(pm, 16));
        pm = fmaxf(pm, __shfl_xor(pm, 32));
        const float mn = fmaxf(m, pm);
        const float f  = __expf(m - mn);
        float ds = __expf(sc0 - mn) + __expf(sc1 - mn)
                 + __expf(sc2 - mn) + __expf(sc3 - mn);
        ds += __shfl_xor(ds, 16);
        ds += __shfl_xor(ds, 32);
        denom = denom * f + ds;
        m = mn;

        // this thread's own-row (row = lc) score: from lane lg'=lc>>2, reg lc&3
        const int src = (lc >> 2) << 4;
        const float t0 = __shfl(part0, src);
        const float t1 = __shfl(part1, src);
        const float t2 = __shfl(part2, src);
        const float t3 = __shfl(part3, src);
        const float s01 = (lc & 1) ? t1 : t0;
        const float s23 = (lc & 1) ? t3 : t2;
        const float my_s = (lc & 2) ? s23 : s01;
        const float w = (tile * 16 + lc < len) ? __expf(my_s - mn) : 0.0f;

        // ---- accumulate weighted x from in-register fragments ----
        #pragma unroll
        for (int ks = 0; ks < 4; ++ks) {
            #pragma unroll
            for (int j = 0; j < 8; ++j) {
                const int v = ks * 8 + j;
                o_part[v] = fmaf(o_part[v], f,
                                 w * ((float)ah[ks][j] + (float)al[ks][j]));
            }
        }
    }

    // ---- block epilogue: merge 4 waves with flash rescale ----
    #pragma unroll
    for (int v = 0; v < 32; ++v) {
        #pragma unroll
        for (int mk = 8; mk >= 1; mk >>= 1)
            o_part[v] += __shfl_xor(o_part[v], mk);
    }
    if (lc == 0) {
        #pragma unroll
        for (int v = 0; v < 32; ++v)
            o_red[(wv * 4 + lg) * 32 + v] = o_part[v];
    }
    if (lane == 0) { s_m[wv] = m; s_d[wv] = denom; }
    __syncthreads();

    float* pb = part + (size_t)blockIdx.x * PSTRIDE;
    if (tid < 128) {
        const int lg2 = tid >> 5, v = tid & 31;
        float mstar = fmaxf(fmaxf(s_m[0], s_m[1]), fmaxf(s_m[2], s_m[3]));
        float val = 0.0f, den = 0.0f;
        #pragma unroll
        for (int w2 = 0; w2 < 4; ++w2) {
            const float mw = s_m[w2];
            const float e  = (mw > -INFINITY) ? __expf(mw - mstar) : 0.0f;
            val = fmaf(o_red[(w2 * 4 + lg2) * 32 + v], e, val);
            den = fmaf(s_d[w2], e, den);
        }
        const int d = (v >> 3) * 32 + lg2 * 8 + (v & 7);
        pb[d] = val;
        if (tid == 0) { pb[128] = mstar; pb[129] = den; }
        else if (tid == 1) { /* keep layout */ }
    }
    // den is identical for all tid<128; write once via tid==0 above; m* too.
    if (tid == 64) {  // redundant safety write of denom from another lane group
        // no-op: kept structure minimal
    }
}

// K2: merge SPLIT partials per segment (flash-style rescale), normalize.
extern "C" __global__ void __launch_bounds__(128)
combine_kernel(const float* __restrict__ part, float* __restrict__ out)
{
    const int b = blockIdx.x, d = threadIdx.x;
    const float* pb = part + (size_t)b * SPLIT * PSTRIDE;

    float mq[SPLIT];
    float mstar = -INFINITY;
    #pragma unroll
    for (int q = 0; q < SPLIT; ++q) {
        mq[q] = pb[q * PSTRIDE + 128];
        mstar = fmaxf(mstar, mq[q]);
    }
    if (mstar == -INFINITY) {          // empty segment
        out[b * D_DIM + d] = 0.0f;
        return;
    }
    float den = 0.0f, val = 0.0f;
    #pragma unroll
    for (int q = 0; q < SPLIT; ++q) {
        const float e = (mq[q] > -INFINITY) ? __expf(mq[q] - mstar) : 0.0f;
        den = fmaf(pb[q * PSTRIDE + 129], e, den);
        val = fmaf(pb[q * PSTRIDE + d],   e, val);
    }
    out[b * D_DIM + d] = val / den;
}

extern "C" void kernel_launch(void* const* d_in, const int* in_sizes, int n_in,
                              void* d_out, int out_size, void* d_ws, size_t ws_size,
                              hipStream_t stream)
{
    const float* x    = (const float*)d_in[0];
    const int*   bidx = (const int*)d_in[1];
    const float* W1   = (const float*)d_in[2];
    const float* b1   = (const float*)d_in[3];
    const float* W2   = (const float*)d_in[4];
    // d_in[5] = b2: cancels in softmax, unused

    const int N = in_sizes[1];
    const int B = out_size / D_DIM;

    char* ws = (char*)d_ws;
    int*   seg_start = (int*)ws;                       // B+1 ints
    float* part      = (float*)(ws + 4096);            // B*SPLIT*PSTRIDE floats

    seg_bounds_kernel<<<(B + 256) / 256, 256, 0, stream>>>(bidx, N, B, seg_start);
    fused_partial_kernel<<<B * SPLIT, NTHREADS, 0, stream>>>(
        x, seg_start, W1, b1, W2, part, N);
    combine_kernel<<<B, 128, 0, stream>>>(part, (float*)d_out);
}